// Round 1
// baseline (423.737 us; speedup 1.0000x reference)
//
#include <hip/hip_runtime.h>
#include <hip/hip_bf16.h>
#include <stdint.h>

#define BATCH 4
#define SEQ 2048
#define DMODEL 1024
#define HEADS 16
#define DKH 64
#define MTOT (BATCH * SEQ)

typedef float  fx4  __attribute__((ext_vector_type(4)));
typedef short  sx8  __attribute__((ext_vector_type(8)));
typedef __bf16 bx8  __attribute__((ext_vector_type(8)));
typedef unsigned short ux4 __attribute__((ext_vector_type(4)));

__device__ __forceinline__ fx4 mfma16(sx8 a, sx8 b, fx4 c) {
  return __builtin_amdgcn_mfma_f32_16x16x32_bf16(
      __builtin_bit_cast(bx8, a), __builtin_bit_cast(bx8, b), c, 0, 0, 0);
}

__device__ __forceinline__ unsigned short f2bf(float x) {
  return __builtin_bit_cast(unsigned short, __float2bfloat16(x));
}

__device__ __forceinline__ void gll16(const void* g, void* l) {
  __builtin_amdgcn_global_load_lds(
      (const __attribute__((address_space(1))) void*)g,
      (__attribute__((address_space(3))) void*)l, 16, 0, 0);
}

// ---------------- weight fp32 -> bf16 convert ----------------
__global__ __launch_bounds__(256) void convert_w(
    const float* __restrict__ s0, const float* __restrict__ s1, const float* __restrict__ s2,
    unsigned short* __restrict__ d0, unsigned short* __restrict__ d1, unsigned short* __restrict__ d2) {
  const float* s = (blockIdx.y == 0) ? s0 : (blockIdx.y == 1) ? s1 : s2;
  unsigned short* d = (blockIdx.y == 0) ? d0 : (blockIdx.y == 1) ? d1 : d2;
  const int n4 = DMODEL * DMODEL / 4;
  for (int i = blockIdx.x * 256 + threadIdx.x; i < n4; i += gridDim.x * 256) {
    fx4 v = ((const fx4*)s)[i];
    ux4 o;
    o.x = f2bf(v.x); o.y = f2bf(v.y); o.z = f2bf(v.z); o.w = f2bf(v.w);
    ((ux4*)d)[i] = o;
  }
}

// ---------------- QKV projection GEMM ----------------
// C[m][n] = sum_k A[m][k] * W[n][k] + bias[n]; A fp32 (reg-staged w/ cvt), W bf16 (global_load_lds)
struct QkvArgs {
  const float* A[3];
  const unsigned short* B[3];
  const float* bias[3];
  unsigned short* C[3];
};

#define BM 128
#define BN 128
#define BK 64

__global__ __launch_bounds__(256) void qkv_gemm(QkvArgs args) {
  const int e = blockIdx.z;
  const float* __restrict__ A = args.A[e];
  const unsigned short* __restrict__ B = args.B[e];
  const float* __restrict__ bias = args.bias[e];
  unsigned short* __restrict__ C = args.C[e];

  const int m0 = blockIdx.y * BM;
  const int n0 = blockIdx.x * BN;

  __shared__ unsigned short As[BM][BK];
  __shared__ unsigned short Bs[BN][BK];

  const int tid  = threadIdx.x;
  const int lane = tid & 63;
  const int wv   = tid >> 6;
  const int wm   = wv >> 1;
  const int wn   = wv & 1;
  const int g    = lane >> 4;
  const int l16  = lane & 15;

  fx4 acc[4][4];
#pragma unroll
  for (int m = 0; m < 4; ++m)
#pragma unroll
    for (int n = 0; n < 4; ++n) acc[m][n] = (fx4){0.f, 0.f, 0.f, 0.f};

  for (int kt = 0; kt < DMODEL / BK; ++kt) {
    const int k0 = kt * BK;
    // stage B tile via async global->LDS (16B)
#pragma unroll
    for (int i = 0; i < 4; ++i) {
      const int c = i * 256 + tid;
      const int row = c >> 3, col8 = c & 7;
      gll16(B + (size_t)(n0 + row) * DMODEL + k0 + col8 * 8, &Bs[0][0] + c * 8);
    }
    // stage A tile: fp32 -> bf16 via registers
#pragma unroll
    for (int i = 0; i < 4; ++i) {
      const int c = i * 256 + tid;
      const int row = c >> 3, col8 = c & 7;
      const float* src = A + (size_t)(m0 + row) * DMODEL + k0 + col8 * 8;
      fx4 a0 = *(const fx4*)src;
      fx4 a1 = *(const fx4*)(src + 4);
      sx8 pk;
      pk[0] = (short)f2bf(a0.x); pk[1] = (short)f2bf(a0.y);
      pk[2] = (short)f2bf(a0.z); pk[3] = (short)f2bf(a0.w);
      pk[4] = (short)f2bf(a1.x); pk[5] = (short)f2bf(a1.y);
      pk[6] = (short)f2bf(a1.z); pk[7] = (short)f2bf(a1.w);
      *(sx8*)(&As[0][0] + c * 8) = pk;
    }
    __syncthreads();

    sx8 af[4][2], bfr[4][2];
#pragma unroll
    for (int m = 0; m < 4; ++m)
#pragma unroll
      for (int kc = 0; kc < 2; ++kc)
        af[m][kc] = *(const sx8*)(&As[wm * 64 + m * 16 + l16][kc * 32 + g * 8]);
#pragma unroll
    for (int n = 0; n < 4; ++n)
#pragma unroll
      for (int kc = 0; kc < 2; ++kc)
        bfr[n][kc] = *(const sx8*)(&Bs[wn * 64 + n * 16 + l16][kc * 32 + g * 8]);
#pragma unroll
    for (int kc = 0; kc < 2; ++kc)
#pragma unroll
      for (int m = 0; m < 4; ++m)
#pragma unroll
        for (int n = 0; n < 4; ++n)
          acc[m][n] = mfma16(af[m][kc], bfr[n][kc], acc[m][n]);
    __syncthreads();
  }

  // epilogue: bias + bf16 store
#pragma unroll
  for (int n = 0; n < 4; ++n) {
    const int gcol = n0 + wn * 64 + n * 16 + l16;
    const float bv = bias[gcol];
#pragma unroll
    for (int m = 0; m < 4; ++m) {
      const int grow = m0 + wm * 64 + m * 16 + g * 4;
#pragma unroll
      for (int r = 0; r < 4; ++r)
        C[(size_t)(grow + r) * DMODEL + gcol] = f2bf(acc[m][n][r] + bv);
    }
  }
}

// ---------------- fused causal attention (flash-style) ----------------
#define QBLK 128
#define KVB 64

__global__ __launch_bounds__(256) void attn(const unsigned short* __restrict__ qp,
                                            const unsigned short* __restrict__ kp,
                                            const unsigned short* __restrict__ vp,
                                            float* __restrict__ ctx) {
  const int qt = blockIdx.x, h = blockIdx.y, b = blockIdx.z;
  const int q0 = qt * QBLK;

  __shared__ unsigned short Ks[KVB][DKH];      // swizzled rows (8 KB)
  __shared__ unsigned short Vt[DKH][KVB];      // transposed V, swizzled (8 KB)
  __shared__ unsigned short Ps[4][32][KVB];    // per-wave P (16 KB)

  const int tid  = threadIdx.x;
  const int lane = tid & 63;
  const int wv   = tid >> 6;
  const int g    = lane >> 4;
  const int l16  = lane & 15;

  const size_t bh = ((size_t)b * SEQ) * DMODEL + (size_t)h * DKH;

  // Q fragments in registers (A operand: row = l16, k = g*8+j per 32-chunk)
  sx8 qf[2][2];
#pragma unroll
  for (int m = 0; m < 2; ++m)
#pragma unroll
    for (int kc = 0; kc < 2; ++kc)
      qf[m][kc] = *(const sx8*)(qp + bh + (size_t)(q0 + wv * 32 + m * 16 + l16) * DMODEL + kc * 32 + g * 8);

  fx4 oacc[2][4];
  float mrow[2][4], lrow[2][4];
#pragma unroll
  for (int m = 0; m < 2; ++m)
#pragma unroll
    for (int nt = 0; nt < 4; ++nt) oacc[m][nt] = (fx4){0.f, 0.f, 0.f, 0.f};
#pragma unroll
  for (int m = 0; m < 2; ++m)
#pragma unroll
    for (int r = 0; r < 4; ++r) { mrow[m][r] = -1e30f; lrow[m][r] = 0.f; }

  const int ntiles = (q0 + QBLK) / KVB;
  for (int t = 0; t < ntiles; ++t) {
    const int kv0 = t * KVB;
    // stage K with pre-swizzled global source (chunk ^= row&7)
#pragma unroll
    for (int i = 0; i < 2; ++i) {
      const int c = i * 256 + tid;
      const int row = c >> 3, col8 = c & 7;
      const int scol = col8 ^ (row & 7);
      gll16(kp + bh + (size_t)(kv0 + row) * DMODEL + scol * 8, &Ks[0][0] + c * 8);
    }
    // stage V transposed + swizzled (reg path)
#pragma unroll
    for (int i = 0; i < 2; ++i) {
      const int c = i * 256 + tid;
      const int kv = c >> 3, d0 = (c & 7) * 8;
      sx8 vvv = *(const sx8*)(vp + bh + (size_t)(kv0 + kv) * DMODEL + d0);
#pragma unroll
      for (int j = 0; j < 8; ++j) {
        const int d = d0 + j;
        const int sl = (kv >> 3) ^ (d & 7);
        Vt[d][sl * 8 + (kv & 7)] = (unsigned short)vvv[j];
      }
    }
    __syncthreads();

    // S = Q K^T
    fx4 sacc[2][4];
#pragma unroll
    for (int m = 0; m < 2; ++m)
#pragma unroll
      for (int nt = 0; nt < 4; ++nt) sacc[m][nt] = (fx4){0.f, 0.f, 0.f, 0.f};

    sx8 kf[4][2];
#pragma unroll
    for (int nt = 0; nt < 4; ++nt) {
      const int row = l16 + 16 * nt;
#pragma unroll
      for (int kc = 0; kc < 2; ++kc)
        kf[nt][kc] = *(const sx8*)(&Ks[row][((kc * 4 + g) ^ (row & 7)) * 8]);
    }
#pragma unroll
    for (int kc = 0; kc < 2; ++kc)
#pragma unroll
      for (int m = 0; m < 2; ++m)
#pragma unroll
        for (int nt = 0; nt < 4; ++nt)
          sacc[m][nt] = mfma16(qf[m][kc], kf[nt][kc], sacc[m][nt]);

    // mask + online softmax (scale AFTER mask, matching reference)
    const float scale = 0.125f;
#pragma unroll
    for (int m = 0; m < 2; ++m) {
      const int qbase = q0 + wv * 32 + m * 16 + g * 4;
#pragma unroll
      for (int r = 0; r < 4; ++r) {
        const int qrow = qbase + r;
        float sv[4];
        float mx = -1e30f;
#pragma unroll
        for (int nt = 0; nt < 4; ++nt) {
          const int kvc = kv0 + nt * 16 + l16;
          float x = sacc[m][nt][r];
          x = (kvc <= qrow) ? x : -1e30f;
          sv[nt] = x;
          mx = fmaxf(mx, x);
        }
        mx = fmaxf(mx, __shfl_xor(mx, 1));
        mx = fmaxf(mx, __shfl_xor(mx, 2));
        mx = fmaxf(mx, __shfl_xor(mx, 4));
        mx = fmaxf(mx, __shfl_xor(mx, 8));
        const float mnew = fmaxf(mrow[m][r], mx * scale);
        const float corr = __expf(mrow[m][r] - mnew);
        mrow[m][r] = mnew;
        float rsum = 0.f;
        const int prow = m * 16 + g * 4 + r;
#pragma unroll
        for (int nt = 0; nt < 4; ++nt) {
          const float p = __expf(sv[nt] * scale - mnew);
          rsum += p;
          const int kvl = nt * 16 + l16;
          const int sch = (kvl >> 3) ^ (prow & 7);
          Ps[wv][prow][sch * 8 + (kvl & 7)] = f2bf(p);
        }
        rsum += __shfl_xor(rsum, 1);
        rsum += __shfl_xor(rsum, 2);
        rsum += __shfl_xor(rsum, 4);
        rsum += __shfl_xor(rsum, 8);
        lrow[m][r] = lrow[m][r] * corr + rsum;
#pragma unroll
        for (int nt = 0; nt < 4; ++nt) oacc[m][nt][r] *= corr;
      }
    }

    // PV: ctx += P @ V  (P from per-wave LDS, V from transposed LDS)
#pragma unroll
    for (int kc = 0; kc < 2; ++kc) {
      sx8 vf[4];
#pragma unroll
      for (int nt = 0; nt < 4; ++nt) {
        const int drow = l16 + 16 * nt;
        vf[nt] = *(const sx8*)(&Vt[drow][((kc * 4 + g) ^ (drow & 7)) * 8]);
      }
#pragma unroll
      for (int m = 0; m < 2; ++m) {
        const int prow = m * 16 + l16;
        sx8 pf = *(const sx8*)(&Ps[wv][prow][((kc * 4 + g) ^ (prow & 7)) * 8]);
#pragma unroll
        for (int nt = 0; nt < 4; ++nt)
          oacc[m][nt] = mfma16(pf, vf[nt], oacc[m][nt]);
      }
    }
    __syncthreads();
  }

  // epilogue: normalize and write fp32 ctx into d_out
#pragma unroll
  for (int m = 0; m < 2; ++m) {
#pragma unroll
    for (int r = 0; r < 4; ++r) {
      const int q = q0 + wv * 32 + m * 16 + g * 4 + r;
      const float inv = 1.0f / lrow[m][r];
#pragma unroll
      for (int nt = 0; nt < 4; ++nt)
        ctx[bh + (size_t)q * DMODEL + nt * 16 + l16] = oacc[m][nt][r] * inv;
    }
  }
}

// ---------------- residual + LayerNorm (in-place on d_out) ----------------
__global__ __launch_bounds__(256) void ln_kernel(const float* __restrict__ qin,
                                                 float* __restrict__ out,
                                                 const float* __restrict__ gamma,
                                                 const float* __restrict__ beta) {
  const int row = blockIdx.x;
  const int tid = threadIdx.x;
  float* orow = out + (size_t)row * DMODEL;
  const float* qr = qin + (size_t)row * DMODEL;

  fx4 cv = ((const fx4*)orow)[tid];
  fx4 qv = ((const fx4*)qr)[tid];
  fx4 x = cv + qv;

  float s  = x.x + x.y + x.z + x.w;
  float ss = x.x * x.x + x.y * x.y + x.z * x.z + x.w * x.w;
#pragma unroll
  for (int off = 1; off < 64; off <<= 1) {
    s  += __shfl_xor(s, off);
    ss += __shfl_xor(ss, off);
  }
  __shared__ float rs[4], rss[4];
  if ((tid & 63) == 0) { rs[tid >> 6] = s; rss[tid >> 6] = ss; }
  __syncthreads();
  s  = rs[0] + rs[1] + rs[2] + rs[3];
  ss = rss[0] + rss[1] + rss[2] + rss[3];

  const float mu   = s * (1.0f / DMODEL);
  const float var  = ss * (1.0f / DMODEL) - mu * mu;
  const float rstd = rsqrtf(var + 1e-5f);

  fx4 gv = ((const fx4*)gamma)[tid];
  fx4 bv = ((const fx4*)beta)[tid];
  fx4 o;
  o.x = (x.x - mu) * rstd * gv.x + bv.x;
  o.y = (x.y - mu) * rstd * gv.y + bv.y;
  o.z = (x.z - mu) * rstd * gv.z + bv.z;
  o.w = (x.w - mu) * rstd * gv.w + bv.w;
  ((fx4*)orow)[tid] = o;
}

// ---------------- host launcher ----------------
extern "C" void kernel_launch(void* const* d_in, const int* in_sizes, int n_in,
                              void* d_out, int out_size, void* d_ws, size_t ws_size,
                              hipStream_t stream) {
  const float* q     = (const float*)d_in[0];
  const float* k     = (const float*)d_in[1];
  const float* v     = (const float*)d_in[2];
  // d_in[3] = trg_mask (int32): causal by construction; applied analytically.
  const float* Wq    = (const float*)d_in[4];
  const float* bq    = (const float*)d_in[5];
  const float* Wk    = (const float*)d_in[6];
  const float* bk    = (const float*)d_in[7];
  const float* Wv    = (const float*)d_in[8];
  const float* bv    = (const float*)d_in[9];
  const float* gamma = (const float*)d_in[10];
  const float* beta  = (const float*)d_in[11];

  unsigned short* Wqb = (unsigned short*)d_ws;
  unsigned short* Wkb = Wqb + (size_t)DMODEL * DMODEL;
  unsigned short* Wvb = Wkb + (size_t)DMODEL * DMODEL;
  unsigned short* qpj = Wvb + (size_t)DMODEL * DMODEL;
  unsigned short* kpj = qpj + (size_t)MTOT * DMODEL;
  unsigned short* vpj = kpj + (size_t)MTOT * DMODEL;

  convert_w<<<dim3(256, 3), 256, 0, stream>>>(Wq, Wk, Wv, Wqb, Wkb, Wvb);

  QkvArgs ga;
  ga.A[0] = q;   ga.A[1] = k;   ga.A[2] = v;
  ga.B[0] = Wqb; ga.B[1] = Wkb; ga.B[2] = Wvb;
  ga.bias[0] = bq; ga.bias[1] = bk; ga.bias[2] = bv;
  ga.C[0] = qpj; ga.C[1] = kpj; ga.C[2] = vpj;
  qkv_gemm<<<dim3(DMODEL / BN, MTOT / BM, 3), 256, 0, stream>>>(ga);

  attn<<<dim3(SEQ / QBLK, HEADS, BATCH), 256, 0, stream>>>(qpj, kpj, vpj, (float*)d_out);

  ln_kernel<<<MTOT, 256, 0, stream>>>(q, (float*)d_out, gamma, beta);
}

// Round 2
// 248.640 us; speedup vs baseline: 1.7042x; 1.7042x over previous
//
#include <hip/hip_runtime.h>
#include <hip/hip_bf16.h>
#include <stdint.h>

#define BATCH 4
#define SEQ 2048
#define DMODEL 1024
#define HEADS 16
#define DKH 64
#define MTOT (BATCH * SEQ)

typedef float  fx4  __attribute__((ext_vector_type(4)));
typedef short  sx8  __attribute__((ext_vector_type(8)));
typedef __bf16 bx8  __attribute__((ext_vector_type(8)));
typedef unsigned short ux4 __attribute__((ext_vector_type(4)));
typedef unsigned int   ux4i __attribute__((ext_vector_type(4)));

__device__ __forceinline__ fx4 mfma16(sx8 a, sx8 b, fx4 c) {
  return __builtin_amdgcn_mfma_f32_16x16x32_bf16(
      __builtin_bit_cast(bx8, a), __builtin_bit_cast(bx8, b), c, 0, 0, 0);
}

__device__ __forceinline__ unsigned short f2bf(float x) {
  return __builtin_bit_cast(unsigned short, __float2bfloat16(x));
}

__device__ __forceinline__ void gll16(const void* g, void* l) {
  __builtin_amdgcn_global_load_lds(
      (const __attribute__((address_space(1))) void*)g,
      (__attribute__((address_space(3))) void*)l, 16, 0, 0);
}

// ---------------- weight fp32 -> bf16 convert ----------------
__global__ __launch_bounds__(256) void convert_w(
    const float* __restrict__ s0, const float* __restrict__ s1, const float* __restrict__ s2,
    unsigned short* __restrict__ d0, unsigned short* __restrict__ d1, unsigned short* __restrict__ d2) {
  const float* s = (blockIdx.y == 0) ? s0 : (blockIdx.y == 1) ? s1 : s2;
  unsigned short* d = (blockIdx.y == 0) ? d0 : (blockIdx.y == 1) ? d1 : d2;
  const int n4 = DMODEL * DMODEL / 4;
  for (int i = blockIdx.x * 256 + threadIdx.x; i < n4; i += gridDim.x * 256) {
    fx4 v = ((const fx4*)s)[i];
    ux4 o;
    o.x = f2bf(v.x); o.y = f2bf(v.y); o.z = f2bf(v.z); o.w = f2bf(v.w);
    ((ux4*)d)[i] = o;
  }
}

// ---------------- QKV projection GEMM ----------------
struct QkvArgs {
  const float* A[3];
  const unsigned short* B[3];
  const float* bias[3];
  unsigned short* C[3];
};

#define BM 128
#define BN 128
#define BK 64

__global__ __launch_bounds__(256) void qkv_gemm(QkvArgs args) {
  const int e = blockIdx.z;
  const float* __restrict__ A = args.A[e];
  const unsigned short* __restrict__ B = args.B[e];
  const float* __restrict__ bias = args.bias[e];
  unsigned short* __restrict__ C = args.C[e];

  const int m0 = blockIdx.y * BM;
  const int n0 = blockIdx.x * BN;

  __shared__ unsigned short As[BM][BK];
  __shared__ unsigned short Bs[BN][BK];

  const int tid  = threadIdx.x;
  const int lane = tid & 63;
  const int wv   = tid >> 6;
  const int wm   = wv >> 1;
  const int wn   = wv & 1;
  const int g    = lane >> 4;
  const int l16  = lane & 15;

  fx4 acc[4][4];
#pragma unroll
  for (int m = 0; m < 4; ++m)
#pragma unroll
    for (int n = 0; n < 4; ++n) acc[m][n] = (fx4){0.f, 0.f, 0.f, 0.f};

  for (int kt = 0; kt < DMODEL / BK; ++kt) {
    const int k0 = kt * BK;
#pragma unroll
    for (int i = 0; i < 4; ++i) {
      const int c = i * 256 + tid;
      const int row = c >> 3, col8 = c & 7;
      gll16(B + (size_t)(n0 + row) * DMODEL + k0 + col8 * 8, &Bs[0][0] + c * 8);
    }
#pragma unroll
    for (int i = 0; i < 4; ++i) {
      const int c = i * 256 + tid;
      const int row = c >> 3, col8 = c & 7;
      const float* src = A + (size_t)(m0 + row) * DMODEL + k0 + col8 * 8;
      fx4 a0 = *(const fx4*)src;
      fx4 a1 = *(const fx4*)(src + 4);
      sx8 pk;
      pk[0] = (short)f2bf(a0.x); pk[1] = (short)f2bf(a0.y);
      pk[2] = (short)f2bf(a0.z); pk[3] = (short)f2bf(a0.w);
      pk[4] = (short)f2bf(a1.x); pk[5] = (short)f2bf(a1.y);
      pk[6] = (short)f2bf(a1.z); pk[7] = (short)f2bf(a1.w);
      *(sx8*)(&As[0][0] + c * 8) = pk;
    }
    __syncthreads();

    sx8 af[4][2], bfr[4][2];
#pragma unroll
    for (int m = 0; m < 4; ++m)
#pragma unroll
      for (int kc = 0; kc < 2; ++kc)
        af[m][kc] = *(const sx8*)(&As[wm * 64 + m * 16 + l16][kc * 32 + g * 8]);
#pragma unroll
    for (int n = 0; n < 4; ++n)
#pragma unroll
      for (int kc = 0; kc < 2; ++kc)
        bfr[n][kc] = *(const sx8*)(&Bs[wn * 64 + n * 16 + l16][kc * 32 + g * 8]);
#pragma unroll
    for (int kc = 0; kc < 2; ++kc)
#pragma unroll
      for (int m = 0; m < 4; ++m)
#pragma unroll
        for (int n = 0; n < 4; ++n)
          acc[m][n] = mfma16(af[m][kc], bfr[n][kc], acc[m][n]);
    __syncthreads();
  }

#pragma unroll
  for (int n = 0; n < 4; ++n) {
    const int gcol = n0 + wn * 64 + n * 16 + l16;
    const float bv = bias[gcol];
#pragma unroll
    for (int m = 0; m < 4; ++m) {
      const int grow = m0 + wm * 64 + m * 16 + g * 4;
#pragma unroll
      for (int r = 0; r < 4; ++r)
        C[(size_t)(grow + r) * DMODEL + gcol] = f2bf(acc[m][n][r] + bv);
    }
  }
}

// ---------------- fused causal attention (flash, swapped-QK, balanced pairs) ----------------
#define QBLK 128
#define KVB 64
#define NQT (SEQ / QBLK)   // 16

__global__ __launch_bounds__(256) void attn(const unsigned short* __restrict__ qp,
                                            const unsigned short* __restrict__ kp,
                                            const unsigned short* __restrict__ vp,
                                            float* __restrict__ ctx) {
  const int pr = blockIdx.x;            // pair index 0..7
  const int h  = blockIdx.y, b = blockIdx.z;

  __shared__ unsigned short Ks[2][KVB][DKH];   // 16 KB, source-swizzled rows
  __shared__ unsigned short Vt[2][DKH][KVB];   // 16 KB, transposed+XOR-swizzled
  __shared__ unsigned short Ps[4][32][KVB];    // 16 KB, per-wave P (swizzled)

  const int tid  = threadIdx.x;
  const int lane = tid & 63;
  const int wv   = tid >> 6;
  const int g    = lane >> 4;
  const int l16  = lane & 15;

  // V staging mapping: each thread owns kv pair (2*kvp, 2*kvp+1) x d-chunk dcc*8..+7
  const int kvp = tid >> 3;   // 0..31
  const int dcc = tid & 7;    // 0..7

  const size_t bh = ((size_t)b * SEQ) * DMODEL + (size_t)h * DKH;
  const int sbase = (lane & 48) + ((lane & 48) >> 2);  // shfl src base for q_local16 = g*4+r

  for (int half = 0; half < 2; ++half) {
    const int qt  = half ? (NQT - 1 - pr) : pr;
    const int q0  = qt * QBLK;
    const int ntl = 2 * (qt + 1);
    const int wq0 = q0 + wv * 32;

    // Q fragments (per-lane data identical for A- or B-operand use)
    sx8 qf[2][2];
#pragma unroll
    for (int m = 0; m < 2; ++m)
#pragma unroll
      for (int kc = 0; kc < 2; ++kc)
        qf[m][kc] = *(const sx8*)(qp + bh + (size_t)(wq0 + m * 16 + l16) * DMODEL + kc * 32 + g * 8);

    fx4 oacc[2][4];
    float mrow[2], lrow[2];
#pragma unroll
    for (int m = 0; m < 2; ++m) {
#pragma unroll
      for (int nt = 0; nt < 4; ++nt) oacc[m][nt] = (fx4){0.f, 0.f, 0.f, 0.f};
      mrow[m] = -1e30f; lrow[m] = 0.f;
    }

    // ---- prologue: stage tile 0 into buffer 0 ----
    {
#pragma unroll
      for (int i = 0; i < 2; ++i) {
        const int c = i * 256 + tid;
        const int row = c >> 3, col8 = c & 7;
        const int scol = col8 ^ (row & 7);
        gll16(kp + bh + (size_t)row * DMODEL + scol * 8, &Ks[0][0][0] + c * 8);
      }
      const unsigned short* vsrc = vp + bh + (size_t)(kvp * 2) * DMODEL + dcc * 8;
      ux4i va = *(const ux4i*)vsrc;
      ux4i vb = *(const ux4i*)(vsrc + DMODEL);
#pragma unroll
      for (int j = 0; j < 8; ++j) {
        const int d = dcc * 8 + j;
        const uint32_t lo = (va[j >> 1] >> ((j & 1) * 16)) & 0xffffu;
        const uint32_t hi = (vb[j >> 1] >> ((j & 1) * 16)) & 0xffffu;
        const int f = (dcc ^ (j & 4)) & 7;
        *(uint32_t*)((char*)&Vt[0][0][0] + d * 128 + (((kvp ^ (f << 2)) & 31) << 2)) = lo | (hi << 16);
      }
      __syncthreads();
    }

    int cur = 0;
    for (int t = 0; t < ntl; ++t) {
      const int kv0 = t * KVB;
      const bool more = (t + 1 < ntl);

      // ---- issue next tile's staging early ----
      ux4i va = (ux4i){0, 0, 0, 0}, vb = (ux4i){0, 0, 0, 0};
      if (more) {
#pragma unroll
        for (int i = 0; i < 2; ++i) {
          const int c = i * 256 + tid;
          const int row = c >> 3, col8 = c & 7;
          const int scol = col8 ^ (row & 7);
          gll16(kp + bh + (size_t)(kv0 + KVB + row) * DMODEL + scol * 8,
                &Ks[cur ^ 1][0][0] + c * 8);
        }
        const unsigned short* vsrc = vp + bh + (size_t)(kv0 + KVB + kvp * 2) * DMODEL + dcc * 8;
        va = *(const ux4i*)vsrc;
        vb = *(const ux4i*)(vsrc + DMODEL);
      }

      // ---- S^T = K . Q^T (swapped operands) ----
      sx8 kf[4][2];
#pragma unroll
      for (int nt = 0; nt < 4; ++nt) {
        const int row = l16 + 16 * nt;
#pragma unroll
        for (int kc = 0; kc < 2; ++kc)
          kf[nt][kc] = *(const sx8*)(&Ks[cur][row][((kc * 4 + g) ^ (row & 7)) * 8]);
      }
      fx4 st[2][4];
#pragma unroll
      for (int m = 0; m < 2; ++m)
#pragma unroll
        for (int nt = 0; nt < 4; ++nt) st[m][nt] = (fx4){0.f, 0.f, 0.f, 0.f};
#pragma unroll
      for (int kc = 0; kc < 2; ++kc)
#pragma unroll
        for (int m = 0; m < 2; ++m)
#pragma unroll
          for (int nt = 0; nt < 4; ++nt)
            st[m][nt] = mfma16(kf[nt][kc], qf[m][kc], st[m][nt]);

      // ---- online softmax, lane-parallel (lane l16 = q row) ----
      const float scale = 0.125f;
      bool mlive[2];
#pragma unroll
      for (int m = 0; m < 2; ++m) {
        mlive[m] = (kv0 <= wq0 + m * 16 + 15);   // wave-uniform
        if (!mlive[m]) continue;
        const int qrow = wq0 + m * 16 + l16;
        if (kv0 + KVB - 1 > wq0 + m * 16) {      // diagonal tile: mask
#pragma unroll
          for (int nt = 0; nt < 4; ++nt)
#pragma unroll
            for (int r = 0; r < 4; ++r) {
              const int kvc = kv0 + nt * 16 + g * 4 + r;
              st[m][nt][r] = (kvc <= qrow) ? st[m][nt][r] : -1e30f;
            }
        }
        float mx = -1e30f;
#pragma unroll
        for (int nt = 0; nt < 4; ++nt)
#pragma unroll
          for (int r = 0; r < 4; ++r) mx = fmaxf(mx, st[m][nt][r]);
        mx = fmaxf(mx, __shfl_xor(mx, 16));
        mx = fmaxf(mx, __shfl_xor(mx, 32));

        const float mnew = fmaxf(mrow[m], mx * scale);
        const float corr = __expf(mrow[m] - mnew);
        mrow[m] = mnew;

        float rsum = 0.f;
#pragma unroll
        for (int nt = 0; nt < 4; ++nt)
#pragma unroll
          for (int r = 0; r < 4; ++r) {
            const float p = __expf(st[m][nt][r] * scale - mnew);
            st[m][nt][r] = p;
            rsum += p;
          }
        rsum += __shfl_xor(rsum, 16);
        rsum += __shfl_xor(rsum, 32);
        lrow[m] = lrow[m] * corr + rsum;

        // pack P row to bf16 pairs, swizzled b32 stores (read layout proven)
        const int prow = m * 16 + l16;
        char* psrow = (char*)&Ps[wv][prow][0];
#pragma unroll
        for (int nt = 0; nt < 4; ++nt)
#pragma unroll
          for (int rr = 0; rr < 2; ++rr) {
            const uint32_t pk = (uint32_t)f2bf(st[m][nt][2 * rr]) |
                                ((uint32_t)f2bf(st[m][nt][2 * rr + 1]) << 16);
            *(uint32_t*)(psrow + ((nt * 2 + (g >> 1)) ^ (prow & 7)) * 16 + (g & 1) * 8 + rr * 4) = pk;
          }

        // broadcast corr to O-layout (q_local16 = g*4+r) and rescale
        float c4[4];
#pragma unroll
        for (int r = 0; r < 4; ++r) c4[r] = __shfl(corr, sbase + r, 64);
#pragma unroll
        for (int nt = 0; nt < 4; ++nt)
#pragma unroll
          for (int r = 0; r < 4; ++r) oacc[m][nt][r] *= c4[r];
      }

      // ---- PV: O += P @ V ----
#pragma unroll
      for (int kc = 0; kc < 2; ++kc) {
        sx8 vf[4];
#pragma unroll
        for (int nt = 0; nt < 4; ++nt) {
          const int d = nt * 16 + l16;
          const int f = ((d >> 3) ^ (d & 4)) & 7;
          vf[nt] = *(const sx8*)((const char*)&Vt[cur][0][0] + d * 128 +
                                 ((((kc * 16 + g * 4) ^ (f << 2)) & 31) << 2));
        }
#pragma unroll
        for (int m = 0; m < 2; ++m) {
          if (!mlive[m]) continue;
          const int prow = m * 16 + l16;
          sx8 pf = *(const sx8*)(&Ps[wv][prow][((kc * 4 + g) ^ (prow & 7)) * 8]);
#pragma unroll
          for (int nt = 0; nt < 4; ++nt)
            oacc[m][nt] = mfma16(pf, vf[nt], oacc[m][nt]);
        }
      }

      // ---- write next tile's transposed V, then barrier ----
      if (more) {
#pragma unroll
        for (int j = 0; j < 8; ++j) {
          const int d = dcc * 8 + j;
          const uint32_t lo = (va[j >> 1] >> ((j & 1) * 16)) & 0xffffu;
          const uint32_t hi = (vb[j >> 1] >> ((j & 1) * 16)) & 0xffffu;
          const int f = (dcc ^ (j & 4)) & 7;
          *(uint32_t*)((char*)&Vt[cur ^ 1][0][0] + d * 128 + (((kvp ^ (f << 2)) & 31) << 2)) = lo | (hi << 16);
        }
      }
      __syncthreads();
      cur ^= 1;
    }

    // ---- epilogue: normalize, write fp32 ctx ----
#pragma unroll
    for (int m = 0; m < 2; ++m) {
      const float inv = 1.0f / lrow[m];
      float i4[4];
#pragma unroll
      for (int r = 0; r < 4; ++r) i4[r] = __shfl(inv, sbase + r, 64);
#pragma unroll
      for (int nt = 0; nt < 4; ++nt)
#pragma unroll
        for (int r = 0; r < 4; ++r)
          ctx[bh + (size_t)(wq0 + m * 16 + g * 4 + r) * DMODEL + nt * 16 + l16] =
              oacc[m][nt][r] * i4[r];
    }
    __syncthreads();
  }
}

// ---------------- residual + LayerNorm (in-place on d_out) ----------------
__global__ __launch_bounds__(256) void ln_kernel(const float* __restrict__ qin,
                                                 float* __restrict__ out,
                                                 const float* __restrict__ gamma,
                                                 const float* __restrict__ beta) {
  const int row = blockIdx.x;
  const int tid = threadIdx.x;
  float* orow = out + (size_t)row * DMODEL;
  const float* qr = qin + (size_t)row * DMODEL;

  fx4 cv = ((const fx4*)orow)[tid];
  fx4 qv = ((const fx4*)qr)[tid];
  fx4 x = cv + qv;

  float s  = x.x + x.y + x.z + x.w;
  float ss = x.x * x.x + x.y * x.y + x.z * x.z + x.w * x.w;
#pragma unroll
  for (int off = 1; off < 64; off <<= 1) {
    s  += __shfl_xor(s, off);
    ss += __shfl_xor(ss, off);
  }
  __shared__ float rs[4], rss[4];
  if ((tid & 63) == 0) { rs[tid >> 6] = s; rss[tid >> 6] = ss; }
  __syncthreads();
  s  = rs[0] + rs[1] + rs[2] + rs[3];
  ss = rss[0] + rss[1] + rss[2] + rss[3];

  const float mu   = s * (1.0f / DMODEL);
  const float var  = ss * (1.0f / DMODEL) - mu * mu;
  const float rstd = rsqrtf(var + 1e-5f);

  fx4 gv = ((const fx4*)gamma)[tid];
  fx4 bv = ((const fx4*)beta)[tid];
  fx4 o;
  o.x = (x.x - mu) * rstd * gv.x + bv.x;
  o.y = (x.y - mu) * rstd * gv.y + bv.y;
  o.z = (x.z - mu) * rstd * gv.z + bv.z;
  o.w = (x.w - mu) * rstd * gv.w + bv.w;
  ((fx4*)orow)[tid] = o;
}

// ---------------- host launcher ----------------
extern "C" void kernel_launch(void* const* d_in, const int* in_sizes, int n_in,
                              void* d_out, int out_size, void* d_ws, size_t ws_size,
                              hipStream_t stream) {
  const float* q     = (const float*)d_in[0];
  const float* k     = (const float*)d_in[1];
  const float* v     = (const float*)d_in[2];
  // d_in[3] = trg_mask (int32): causal by construction; applied analytically.
  const float* Wq    = (const float*)d_in[4];
  const float* bq    = (const float*)d_in[5];
  const float* Wk    = (const float*)d_in[6];
  const float* bk    = (const float*)d_in[7];
  const float* Wv    = (const float*)d_in[8];
  const float* bv    = (const float*)d_in[9];
  const float* gamma = (const float*)d_in[10];
  const float* beta  = (const float*)d_in[11];

  unsigned short* Wqb = (unsigned short*)d_ws;
  unsigned short* Wkb = Wqb + (size_t)DMODEL * DMODEL;
  unsigned short* Wvb = Wkb + (size_t)DMODEL * DMODEL;
  unsigned short* qpj = Wvb + (size_t)DMODEL * DMODEL;
  unsigned short* kpj = qpj + (size_t)MTOT * DMODEL;
  unsigned short* vpj = kpj + (size_t)MTOT * DMODEL;

  convert_w<<<dim3(256, 3), 256, 0, stream>>>(Wq, Wk, Wv, Wqb, Wkb, Wvb);

  QkvArgs ga;
  ga.A[0] = q;   ga.A[1] = k;   ga.A[2] = v;
  ga.B[0] = Wqb; ga.B[1] = Wkb; ga.B[2] = Wvb;
  ga.bias[0] = bq; ga.bias[1] = bk; ga.bias[2] = bv;
  ga.C[0] = qpj; ga.C[1] = kpj; ga.C[2] = vpj;
  qkv_gemm<<<dim3(DMODEL / BN, MTOT / BM, 3), 256, 0, stream>>>(ga);

  attn<<<dim3(NQT / 2, HEADS, BATCH), 256, 0, stream>>>(qpj, kpj, vpj, (float*)d_out);

  ln_kernel<<<MTOT, 256, 0, stream>>>(q, (float*)d_out, gamma, beta);
}

// Round 3
// 238.207 us; speedup vs baseline: 1.7789x; 1.0438x over previous
//
#include <hip/hip_runtime.h>
#include <hip/hip_bf16.h>
#include <stdint.h>

#define BATCH 4
#define SEQ 2048
#define DMODEL 1024
#define HEADS 16
#define DKH 64
#define MTOT (BATCH * SEQ)

typedef float  fx4  __attribute__((ext_vector_type(4)));
typedef short  sx8  __attribute__((ext_vector_type(8)));
typedef __bf16 bx8  __attribute__((ext_vector_type(8)));
typedef unsigned short ux4 __attribute__((ext_vector_type(4)));
typedef unsigned int   ux4i __attribute__((ext_vector_type(4)));

__device__ __forceinline__ fx4 mfma16(sx8 a, sx8 b, fx4 c) {
  return __builtin_amdgcn_mfma_f32_16x16x32_bf16(
      __builtin_bit_cast(bx8, a), __builtin_bit_cast(bx8, b), c, 0, 0, 0);
}

__device__ __forceinline__ unsigned short f2bf(float x) {
  return __builtin_bit_cast(unsigned short, __float2bfloat16(x));
}

__device__ __forceinline__ void gll16(const void* g, void* l) {
  __builtin_amdgcn_global_load_lds(
      (const __attribute__((address_space(1))) void*)g,
      (__attribute__((address_space(3))) void*)l, 16, 0, 0);
}

// ---------------- weight fp32 -> bf16 convert ----------------
__global__ __launch_bounds__(256) void convert_w(
    const float* __restrict__ s0, const float* __restrict__ s1, const float* __restrict__ s2,
    unsigned short* __restrict__ d0, unsigned short* __restrict__ d1, unsigned short* __restrict__ d2) {
  const float* s = (blockIdx.y == 0) ? s0 : (blockIdx.y == 1) ? s1 : s2;
  unsigned short* d = (blockIdx.y == 0) ? d0 : (blockIdx.y == 1) ? d1 : d2;
  const int n4 = DMODEL * DMODEL / 4;
  for (int i = blockIdx.x * 256 + threadIdx.x; i < n4; i += gridDim.x * 256) {
    fx4 v = ((const fx4*)s)[i];
    ux4 o;
    o.x = f2bf(v.x); o.y = f2bf(v.y); o.z = f2bf(v.z); o.w = f2bf(v.w);
    ((ux4*)d)[i] = o;
  }
}

// ---------------- activation fp32 -> bf16 convert ----------------
__global__ __launch_bounds__(256) void convert_act(const float* __restrict__ s,
                                                   unsigned short* __restrict__ d) {
  const int n4 = MTOT * DMODEL / 4;
  for (int i = blockIdx.x * 256 + threadIdx.x; i < n4; i += gridDim.x * 256) {
    fx4 v = ((const fx4*)s)[i];
    ux4 o;
    o.x = f2bf(v.x); o.y = f2bf(v.y); o.z = f2bf(v.z); o.w = f2bf(v.w);
    ((ux4*)d)[i] = o;
  }
}

// ---------------- projection GEMM: C[m][n] = A[m]·W[n] + bias[n] ----------------
// A bf16 [MTOT][DMODEL], W bf16 [DMODEL][DMODEL] (row n = output col), both via global_load_lds.
#define GBM 128
#define GBN 128
#define GBK 64
#define NBLK ((MTOT / GBM) * (DMODEL / GBN))   // 64*8 = 512

__global__ __launch_bounds__(256) void gemm_bf16(const unsigned short* __restrict__ A,
                                                 const unsigned short* __restrict__ B,
                                                 const float* __restrict__ bias,
                                                 unsigned short* __restrict__ C) {
  // XCD-chunked swizzle: XCD x owns a contiguous band of m-panels (all n),
  // so its A panels (256KB each) + full B (2MB) stay L2-resident.
  const int lin = blockIdx.x;                  // 0..511
  const int swz = (lin & 7) * (NBLK / 8) + (lin >> 3);
  const int m0 = (swz >> 3) * GBM;
  const int n0 = (swz & 7) * GBN;

  __shared__ unsigned short As[GBM][GBK];
  __shared__ unsigned short Bs[GBN][GBK];

  const int tid  = threadIdx.x;
  const int lane = tid & 63;
  const int wv   = tid >> 6;
  const int wm   = wv >> 1;
  const int wn   = wv & 1;
  const int g    = lane >> 4;
  const int l16  = lane & 15;

  fx4 acc[4][4];
#pragma unroll
  for (int m = 0; m < 4; ++m)
#pragma unroll
    for (int n = 0; n < 4; ++n) acc[m][n] = (fx4){0.f, 0.f, 0.f, 0.f};

  for (int kt = 0; kt < DMODEL / GBK; ++kt) {
    const int k0 = kt * GBK;
#pragma unroll
    for (int i = 0; i < 4; ++i) {
      const int c = i * 256 + tid;
      const int row = c >> 3, col8 = c & 7;
      gll16(A + (size_t)(m0 + row) * DMODEL + k0 + col8 * 8, &As[0][0] + c * 8);
      gll16(B + (size_t)(n0 + row) * DMODEL + k0 + col8 * 8, &Bs[0][0] + c * 8);
    }
    __syncthreads();

    sx8 af[4][2], bfr[4][2];
#pragma unroll
    for (int m = 0; m < 4; ++m)
#pragma unroll
      for (int kc = 0; kc < 2; ++kc)
        af[m][kc] = *(const sx8*)(&As[wm * 64 + m * 16 + l16][kc * 32 + g * 8]);
#pragma unroll
    for (int n = 0; n < 4; ++n)
#pragma unroll
      for (int kc = 0; kc < 2; ++kc)
        bfr[n][kc] = *(const sx8*)(&Bs[wn * 64 + n * 16 + l16][kc * 32 + g * 8]);
#pragma unroll
    for (int kc = 0; kc < 2; ++kc)
#pragma unroll
      for (int m = 0; m < 4; ++m)
#pragma unroll
        for (int n = 0; n < 4; ++n)
          acc[m][n] = mfma16(af[m][kc], bfr[n][kc], acc[m][n]);
    __syncthreads();
  }

#pragma unroll
  for (int n = 0; n < 4; ++n) {
    const int gcol = n0 + wn * 64 + n * 16 + l16;
    const float bv = bias[gcol];
#pragma unroll
    for (int m = 0; m < 4; ++m) {
      const int grow = m0 + wm * 64 + m * 16 + g * 4;
#pragma unroll
      for (int r = 0; r < 4; ++r)
        C[(size_t)(grow + r) * DMODEL + gcol] = f2bf(acc[m][n][r] + bv);
    }
  }
}

// ---------------- fused causal attention (flash, swapped-QK, balanced pairs) ----------------
#define QBLK 128
#define KVB 64
#define NQT (SEQ / QBLK)   // 16

__global__ __launch_bounds__(256) void attn(const unsigned short* __restrict__ qp,
                                            const unsigned short* __restrict__ kp,
                                            const unsigned short* __restrict__ vp,
                                            float* __restrict__ ctx) {
  const int pr = blockIdx.x;            // pair index 0..7
  const int h  = blockIdx.y, b = blockIdx.z;

  __shared__ unsigned short Ks[2][KVB][DKH];   // 16 KB, source-swizzled rows
  __shared__ unsigned short Vt[2][DKH][KVB];   // 16 KB, transposed+XOR-swizzled
  __shared__ unsigned short Ps[4][32][KVB];    // 16 KB, per-wave P (swizzled)

  const int tid  = threadIdx.x;
  const int lane = tid & 63;
  const int wv   = tid >> 6;
  const int g    = lane >> 4;
  const int l16  = lane & 15;

  // V staging mapping: each thread owns kv pair (2*kvp, 2*kvp+1) x d-chunk dcc*8..+7
  const int kvp = tid >> 3;   // 0..31
  const int dcc = tid & 7;    // 0..7

  const size_t bh = ((size_t)b * SEQ) * DMODEL + (size_t)h * DKH;
  const int sbase = (lane & 48) + ((lane & 48) >> 2);  // shfl src base for q_local16 = g*4+r

  for (int half = 0; half < 2; ++half) {
    const int qt  = half ? (NQT - 1 - pr) : pr;
    const int q0  = qt * QBLK;
    const int ntl = 2 * (qt + 1);
    const int wq0 = q0 + wv * 32;

    // Q fragments (per-lane data identical for A- or B-operand use)
    sx8 qf[2][2];
#pragma unroll
    for (int m = 0; m < 2; ++m)
#pragma unroll
      for (int kc = 0; kc < 2; ++kc)
        qf[m][kc] = *(const sx8*)(qp + bh + (size_t)(wq0 + m * 16 + l16) * DMODEL + kc * 32 + g * 8);

    fx4 oacc[2][4];
    float mrow[2], lrow[2];
#pragma unroll
    for (int m = 0; m < 2; ++m) {
#pragma unroll
      for (int nt = 0; nt < 4; ++nt) oacc[m][nt] = (fx4){0.f, 0.f, 0.f, 0.f};
      mrow[m] = -1e30f; lrow[m] = 0.f;
    }

    // ---- prologue: stage tile 0 into buffer 0 ----
    {
#pragma unroll
      for (int i = 0; i < 2; ++i) {
        const int c = i * 256 + tid;
        const int row = c >> 3, col8 = c & 7;
        const int scol = col8 ^ (row & 7);
        gll16(kp + bh + (size_t)row * DMODEL + scol * 8, &Ks[0][0][0] + c * 8);
      }
      const unsigned short* vsrc = vp + bh + (size_t)(kvp * 2) * DMODEL + dcc * 8;
      ux4i va = *(const ux4i*)vsrc;
      ux4i vb = *(const ux4i*)(vsrc + DMODEL);
#pragma unroll
      for (int j = 0; j < 8; ++j) {
        const int d = dcc * 8 + j;
        const uint32_t lo = (va[j >> 1] >> ((j & 1) * 16)) & 0xffffu;
        const uint32_t hi = (vb[j >> 1] >> ((j & 1) * 16)) & 0xffffu;
        const int f = (dcc ^ (j & 4)) & 7;
        *(uint32_t*)((char*)&Vt[0][0][0] + d * 128 + (((kvp ^ (f << 2)) & 31) << 2)) = lo | (hi << 16);
      }
      __syncthreads();
    }

    int cur = 0;
    for (int t = 0; t < ntl; ++t) {
      const int kv0 = t * KVB;
      const bool more = (t + 1 < ntl);

      // ---- issue next tile's staging early ----
      ux4i va = (ux4i){0, 0, 0, 0}, vb = (ux4i){0, 0, 0, 0};
      if (more) {
#pragma unroll
        for (int i = 0; i < 2; ++i) {
          const int c = i * 256 + tid;
          const int row = c >> 3, col8 = c & 7;
          const int scol = col8 ^ (row & 7);
          gll16(kp + bh + (size_t)(kv0 + KVB + row) * DMODEL + scol * 8,
                &Ks[cur ^ 1][0][0] + c * 8);
        }
        const unsigned short* vsrc = vp + bh + (size_t)(kv0 + KVB + kvp * 2) * DMODEL + dcc * 8;
        va = *(const ux4i*)vsrc;
        vb = *(const ux4i*)(vsrc + DMODEL);
      }

      // ---- S^T = K . Q^T (swapped operands) ----
      sx8 kf[4][2];
#pragma unroll
      for (int nt = 0; nt < 4; ++nt) {
        const int row = l16 + 16 * nt;
#pragma unroll
        for (int kc = 0; kc < 2; ++kc)
          kf[nt][kc] = *(const sx8*)(&Ks[cur][row][((kc * 4 + g) ^ (row & 7)) * 8]);
      }
      fx4 st[2][4];
#pragma unroll
      for (int m = 0; m < 2; ++m)
#pragma unroll
        for (int nt = 0; nt < 4; ++nt) st[m][nt] = (fx4){0.f, 0.f, 0.f, 0.f};
#pragma unroll
      for (int kc = 0; kc < 2; ++kc)
#pragma unroll
        for (int m = 0; m < 2; ++m)
#pragma unroll
          for (int nt = 0; nt < 4; ++nt)
            st[m][nt] = mfma16(kf[nt][kc], qf[m][kc], st[m][nt]);

      // ---- online softmax, lane-parallel (lane l16 = q row) ----
      const float scale = 0.125f;
      bool mlive[2];
#pragma unroll
      for (int m = 0; m < 2; ++m) {
        mlive[m] = (kv0 <= wq0 + m * 16 + 15);   // wave-uniform
        if (!mlive[m]) continue;
        const int qrow = wq0 + m * 16 + l16;
        if (kv0 + KVB - 1 > wq0 + m * 16) {      // diagonal tile: mask
#pragma unroll
          for (int nt = 0; nt < 4; ++nt)
#pragma unroll
            for (int r = 0; r < 4; ++r) {
              const int kvc = kv0 + nt * 16 + g * 4 + r;
              st[m][nt][r] = (kvc <= qrow) ? st[m][nt][r] : -1e30f;
            }
        }
        float mx = -1e30f;
#pragma unroll
        for (int nt = 0; nt < 4; ++nt)
#pragma unroll
          for (int r = 0; r < 4; ++r) mx = fmaxf(mx, st[m][nt][r]);
        mx = fmaxf(mx, __shfl_xor(mx, 16));
        mx = fmaxf(mx, __shfl_xor(mx, 32));

        const float mnew = fmaxf(mrow[m], mx * scale);
        const float corr = __expf(mrow[m] - mnew);
        mrow[m] = mnew;

        float rsum = 0.f;
#pragma unroll
        for (int nt = 0; nt < 4; ++nt)
#pragma unroll
          for (int r = 0; r < 4; ++r) {
            const float p = __expf(st[m][nt][r] * scale - mnew);
            st[m][nt][r] = p;
            rsum += p;
          }
        rsum += __shfl_xor(rsum, 16);
        rsum += __shfl_xor(rsum, 32);
        lrow[m] = lrow[m] * corr + rsum;

        // pack P row to bf16 pairs, swizzled b32 stores (read layout proven)
        const int prow = m * 16 + l16;
        char* psrow = (char*)&Ps[wv][prow][0];
#pragma unroll
        for (int nt = 0; nt < 4; ++nt)
#pragma unroll
          for (int rr = 0; rr < 2; ++rr) {
            const uint32_t pk = (uint32_t)f2bf(st[m][nt][2 * rr]) |
                                ((uint32_t)f2bf(st[m][nt][2 * rr + 1]) << 16);
            *(uint32_t*)(psrow + ((nt * 2 + (g >> 1)) ^ (prow & 7)) * 16 + (g & 1) * 8 + rr * 4) = pk;
          }

        // broadcast corr to O-layout (q_local16 = g*4+r) and rescale
        float c4[4];
#pragma unroll
        for (int r = 0; r < 4; ++r) c4[r] = __shfl(corr, sbase + r, 64);
#pragma unroll
        for (int nt = 0; nt < 4; ++nt)
#pragma unroll
          for (int r = 0; r < 4; ++r) oacc[m][nt][r] *= c4[r];
      }

      // ---- PV: O += P @ V ----
#pragma unroll
      for (int kc = 0; kc < 2; ++kc) {
        sx8 vf[4];
#pragma unroll
        for (int nt = 0; nt < 4; ++nt) {
          const int d = nt * 16 + l16;
          const int f = ((d >> 3) ^ (d & 4)) & 7;
          vf[nt] = *(const sx8*)((const char*)&Vt[cur][0][0] + d * 128 +
                                 ((((kc * 16 + g * 4) ^ (f << 2)) & 31) << 2));
        }
#pragma unroll
        for (int m = 0; m < 2; ++m) {
          if (!mlive[m]) continue;
          const int prow = m * 16 + l16;
          sx8 pf = *(const sx8*)(&Ps[wv][prow][((kc * 4 + g) ^ (prow & 7)) * 8]);
#pragma unroll
          for (int nt = 0; nt < 4; ++nt)
            oacc[m][nt] = mfma16(pf, vf[nt], oacc[m][nt]);
        }
      }

      // ---- write next tile's transposed V, then barrier ----
      if (more) {
#pragma unroll
        for (int j = 0; j < 8; ++j) {
          const int d = dcc * 8 + j;
          const uint32_t lo = (va[j >> 1] >> ((j & 1) * 16)) & 0xffffu;
          const uint32_t hi = (vb[j >> 1] >> ((j & 1) * 16)) & 0xffffu;
          const int f = (dcc ^ (j & 4)) & 7;
          *(uint32_t*)((char*)&Vt[cur ^ 1][0][0] + d * 128 + (((kvp ^ (f << 2)) & 31) << 2)) = lo | (hi << 16);
        }
      }
      __syncthreads();
      cur ^= 1;
    }

    // ---- epilogue: normalize, write fp32 ctx ----
#pragma unroll
    for (int m = 0; m < 2; ++m) {
      const float inv = 1.0f / lrow[m];
      float i4[4];
#pragma unroll
      for (int r = 0; r < 4; ++r) i4[r] = __shfl(inv, sbase + r, 64);
#pragma unroll
      for (int nt = 0; nt < 4; ++nt)
#pragma unroll
        for (int r = 0; r < 4; ++r)
          ctx[bh + (size_t)(wq0 + m * 16 + g * 4 + r) * DMODEL + nt * 16 + l16] =
              oacc[m][nt][r] * i4[r];
    }
    __syncthreads();
  }
}

// ---------------- residual + LayerNorm (in-place on d_out) ----------------
__global__ __launch_bounds__(256) void ln_kernel(const float* __restrict__ qin,
                                                 float* __restrict__ out,
                                                 const float* __restrict__ gamma,
                                                 const float* __restrict__ beta) {
  const int row = blockIdx.x;
  const int tid = threadIdx.x;
  float* orow = out + (size_t)row * DMODEL;
  const float* qr = qin + (size_t)row * DMODEL;

  fx4 cv = ((const fx4*)orow)[tid];
  fx4 qv = ((const fx4*)qr)[tid];
  fx4 x = cv + qv;

  float s  = x.x + x.y + x.z + x.w;
  float ss = x.x * x.x + x.y * x.y + x.z * x.z + x.w * x.w;
#pragma unroll
  for (int off = 1; off < 64; off <<= 1) {
    s  += __shfl_xor(s, off);
    ss += __shfl_xor(ss, off);
  }
  __shared__ float rs[4], rss[4];
  if ((tid & 63) == 0) { rs[tid >> 6] = s; rss[tid >> 6] = ss; }
  __syncthreads();
  s  = rs[0] + rs[1] + rs[2] + rs[3];
  ss = rss[0] + rss[1] + rss[2] + rss[3];

  const float mu   = s * (1.0f / DMODEL);
  const float var  = ss * (1.0f / DMODEL) - mu * mu;
  const float rstd = rsqrtf(var + 1e-5f);

  fx4 gv = ((const fx4*)gamma)[tid];
  fx4 bv = ((const fx4*)beta)[tid];
  fx4 o;
  o.x = (x.x - mu) * rstd * gv.x + bv.x;
  o.y = (x.y - mu) * rstd * gv.y + bv.y;
  o.z = (x.z - mu) * rstd * gv.z + bv.z;
  o.w = (x.w - mu) * rstd * gv.w + bv.w;
  ((fx4*)orow)[tid] = o;
}

// ---------------- host launcher ----------------
extern "C" void kernel_launch(void* const* d_in, const int* in_sizes, int n_in,
                              void* d_out, int out_size, void* d_ws, size_t ws_size,
                              hipStream_t stream) {
  const float* q     = (const float*)d_in[0];
  const float* k     = (const float*)d_in[1];
  const float* v     = (const float*)d_in[2];
  // d_in[3] = trg_mask (int32): causal by construction; applied analytically.
  const float* Wq    = (const float*)d_in[4];
  const float* bq    = (const float*)d_in[5];
  const float* Wk    = (const float*)d_in[6];
  const float* bk    = (const float*)d_in[7];
  const float* Wv    = (const float*)d_in[8];
  const float* bv    = (const float*)d_in[9];
  const float* gamma = (const float*)d_in[10];
  const float* beta  = (const float*)d_in[11];

  unsigned short* Wqb = (unsigned short*)d_ws;
  unsigned short* Wkb = Wqb + (size_t)DMODEL * DMODEL;
  unsigned short* Wvb = Wkb + (size_t)DMODEL * DMODEL;
  unsigned short* qpj = Wvb + (size_t)DMODEL * DMODEL;
  unsigned short* kpj = qpj + (size_t)MTOT * DMODEL;
  unsigned short* vpj = kpj + (size_t)MTOT * DMODEL;
  unsigned short* Abf = vpj + (size_t)MTOT * DMODEL;   // reused for q,k,v in turn

  convert_w<<<dim3(256, 3), 256, 0, stream>>>(Wq, Wk, Wv, Wqb, Wkb, Wvb);

  convert_act<<<1024, 256, 0, stream>>>(q, Abf);
  gemm_bf16<<<NBLK, 256, 0, stream>>>(Abf, Wqb, bq, qpj);
  convert_act<<<1024, 256, 0, stream>>>(k, Abf);
  gemm_bf16<<<NBLK, 256, 0, stream>>>(Abf, Wkb, bk, kpj);
  convert_act<<<1024, 256, 0, stream>>>(v, Abf);
  gemm_bf16<<<NBLK, 256, 0, stream>>>(Abf, Wvb, bv, vpj);

  attn<<<dim3(NQT / 2, HEADS, BATCH), 256, 0, stream>>>(qpj, kpj, vpj, (float*)d_out);

  ln_kernel<<<MTOT, 256, 0, stream>>>(q, (float*)d_out, gamma, beta);
}